// Round 2
// baseline (269.893 us; speedup 1.0000x reference)
//
#include <hip/hip_runtime.h>
#include <hip/hip_bf16.h>
#include <cstddef>
#include <cmath>

// Problem constants: B=4, N=1024, H=16, hd=64, EMB=1024, M=B*N=4096
// split order in reference: K, Q, V (cols 0..1023 = K, 1024..2047 = Q, 2048.. = V)

typedef _Float16 f16x8 __attribute__((ext_vector_type(8)));
typedef float    f32x4 __attribute__((ext_vector_type(4)));

#define LOG2E 1.4426950408889634f

// ---------------------------------------------------------------------------
// fp32 -> f16 elementwise convert (vectorized 8/thread)
__global__ __launch_bounds__(256) void cvt_f32_f16(
    const float* __restrict__ in, _Float16* __restrict__ out, int n8)
{
    int i = blockIdx.x * 256 + threadIdx.x;
    if (i < n8) {
        const float4* p = (const float4*)in;
        float4 v0 = p[i * 2], v1 = p[i * 2 + 1];
        f16x8 o;
        o[0] = (_Float16)v0.x; o[1] = (_Float16)v0.y; o[2] = (_Float16)v0.z; o[3] = (_Float16)v0.w;
        o[4] = (_Float16)v1.x; o[5] = (_Float16)v1.y; o[6] = (_Float16)v1.z; o[7] = (_Float16)v1.w;
        *(f16x8*)(out + (size_t)i * 8) = o;
    }
}

// ---------------------------------------------------------------------------
// fp32 [R][C] -> f16 [C][R]  (tiled 64x64 via LDS)
__global__ __launch_bounds__(256) void transpose_f32_to_f16(
    const float* __restrict__ in, _Float16* __restrict__ out, int R, int C)
{
    __shared__ float tile[64][65];
    int r0 = blockIdx.y * 64, c0 = blockIdx.x * 64;
    int t = threadIdx.x;
#pragma unroll
    for (int p = 0; p < 4; ++p) {
        int lin = p * 256 + t;           // 1024 float4-chunks
        int row = lin >> 4;
        int c4 = (lin & 15) * 4;
        float4 v = *(const float4*)(in + (size_t)(r0 + row) * C + c0 + c4);
        tile[row][c4] = v.x; tile[row][c4 + 1] = v.y;
        tile[row][c4 + 2] = v.z; tile[row][c4 + 3] = v.w;
    }
    __syncthreads();
#pragma unroll
    for (int p = 0; p < 2; ++p) {
        int lin = p * 256 + t;           // 512 f16x8-chunks
        int oc = lin >> 3;
        int ch = (lin & 7) * 8;
        f16x8 o;
#pragma unroll
        for (int e = 0; e < 8; ++e) o[e] = (_Float16)tile[ch + e][oc];
        *(f16x8*)(out + (size_t)(c0 + oc) * R + r0 + ch) = o;
    }
}

// ---------------------------------------------------------------------------
// f16 [R][C] -> f16 [C][R] per head (grid.z = heads)
__global__ __launch_bounds__(256) void transpose_f16(
    const _Float16* __restrict__ in, _Float16* __restrict__ out, int R, int C)
{
    __shared__ _Float16 tile[64][72];    // 144B row stride: multiple of 16B, +pad
    const _Float16* inh = in + (size_t)blockIdx.z * R * C;
    _Float16* outh = out + (size_t)blockIdx.z * R * C;
    int r0 = blockIdx.y * 64, c0 = blockIdx.x * 64;
    int t = threadIdx.x;
#pragma unroll
    for (int p = 0; p < 2; ++p) {
        int lin = p * 256 + t;
        int row = lin >> 3;
        int ch = (lin & 7) * 8;
        f16x8 v = *(const f16x8*)(inh + (size_t)(r0 + row) * C + c0 + ch);
        *(f16x8*)&tile[row][ch] = v;
    }
    __syncthreads();
#pragma unroll
    for (int p = 0; p < 2; ++p) {
        int lin = p * 256 + t;
        int oc = lin >> 3;
        int ch = (lin & 7) * 8;
        f16x8 o;
#pragma unroll
        for (int e = 0; e < 8; ++e) o[e] = tile[ch + e][oc];
        *(f16x8*)(outh + (size_t)(c0 + oc) * R + r0 + ch) = o;
    }
}

// ---------------------------------------------------------------------------
// f16 MFMA GEMM: C[M][Nn] = A[M][K] * Bt[Nn][K]^T + bias
// 128x128 tile, BK=64, 4 waves (2x2), each wave 64x64 (4x4 frags of 16x16x32).
// EPI=0: fp32 output + bias.  EPI=1: qkv epilogue -> scatter K/Q/V heads (f16).
template <int EPI>
__global__ __launch_bounds__(256, 2) void gemm_f16(
    const _Float16* __restrict__ A, const _Float16* __restrict__ Bt,
    const float* __restrict__ bias, float* __restrict__ Cout,
    _Float16* __restrict__ Kh, _Float16* __restrict__ Qh, _Float16* __restrict__ Vh,
    int M, int Nn, int Kk)
{
    __shared__ _Float16 As[128][72];
    __shared__ _Float16 Bs[128][72];
    int m0 = blockIdx.y * 128, n0 = blockIdx.x * 128;
    int t = threadIdx.x, lane = t & 63, wid = t >> 6;
    int wr = (wid >> 1) * 64, wc = (wid & 1) * 64;
    int lr = lane & 15, lg = lane >> 4;

    f32x4 acc[4][4] = {};

    for (int k0 = 0; k0 < Kk; k0 += 64) {
#pragma unroll
        for (int p = 0; p < 4; ++p) {
            int lin = p * 256 + t;       // 1024 16B chunks per tile
            int row = lin >> 3;
            int ch = (lin & 7) * 8;
            *(f16x8*)&As[row][ch] = *(const f16x8*)(A + (size_t)(m0 + row) * Kk + k0 + ch);
            *(f16x8*)&Bs[row][ch] = *(const f16x8*)(Bt + (size_t)(n0 + row) * Kk + k0 + ch);
        }
        __syncthreads();
#pragma unroll
        for (int kk = 0; kk < 2; ++kk) {
            f16x8 af[4], bfr[4];
#pragma unroll
            for (int i = 0; i < 4; ++i) {
                af[i]  = *(const f16x8*)&As[wr + i * 16 + lr][kk * 32 + lg * 8];
                bfr[i] = *(const f16x8*)&Bs[wc + i * 16 + lr][kk * 32 + lg * 8];
            }
#pragma unroll
            for (int i = 0; i < 4; ++i)
#pragma unroll
                for (int jn = 0; jn < 4; ++jn)
                    acc[i][jn] = __builtin_amdgcn_mfma_f32_16x16x32_f16(
                        af[i], bfr[jn], acc[i][jn], 0, 0, 0);
        }
        __syncthreads();
    }

    // epilogue: C/D layout col = lane&15, row = (lane>>4)*4 + j  [m89-verified]
#pragma unroll
    for (int i = 0; i < 4; ++i)
#pragma unroll
        for (int jn = 0; jn < 4; ++jn) {
            int gc = n0 + wc + jn * 16 + lr;
            float bv = bias[gc];
#pragma unroll
            for (int j = 0; j < 4; ++j) {
                int gr = m0 + wr + i * 16 + lg * 4 + j;
                float v = acc[i][jn][j] + bv;
                if constexpr (EPI == 0) {
                    Cout[(size_t)gr * Nn + gc] = v;
                } else {
                    int sec = gc >> 10, idx = gc & 1023;
                    int h = idx >> 6, d = idx & 63;
                    int bb = gr >> 10, pos = gr & 1023;
                    size_t hoff = (((size_t)(bb * 16 + h) * 1024) + pos) * 64 + d;
                    if (sec == 0)      Kh[hoff] = (_Float16)v;
                    else if (sec == 1) Qh[hoff] = (_Float16)(v * (0.125f * LOG2E));
                    else               Vh[hoff] = (_Float16)v;
                }
            }
        }
}

// ---------------------------------------------------------------------------
// Flash attention: grid = (16 q-tiles, 64 b*h). 4 waves x 16 q-rows, KV tile 32.
// Q pre-scaled by 0.125*log2(e); softmax in exp2 domain.
// Qh/Kh: [bh][n][64], Vt: [bh][64][n], attO: [B*N][H*64]
__global__ __launch_bounds__(256, 2) void attn_kernel(
    const _Float16* __restrict__ Qh, const _Float16* __restrict__ Kh,
    const _Float16* __restrict__ Vt, _Float16* __restrict__ attO)
{
    __shared__ _Float16 Pl[4][16][40];   // per-wave P^T staging; 80B stride = 16B-aligned
    int bh = blockIdx.y;
    int b = bh >> 4, h = bh & 15;
    int wid = threadIdx.x >> 6, lane = threadIdx.x & 63;
    int lr = lane & 15, lg = lane >> 4;
    int q0 = blockIdx.x * 64 + wid * 16;
    const _Float16* Qb = Qh + (size_t)bh * (1024 * 64);
    const _Float16* Kb = Kh + (size_t)bh * (1024 * 64);
    const _Float16* Vb = Vt + (size_t)bh * (64 * 1024);

    f16x8 qf[2];
#pragma unroll
    for (int kk = 0; kk < 2; ++kk)
        qf[kk] = *(const f16x8*)(Qb + (size_t)(q0 + lr) * 64 + kk * 32 + lg * 8);

    float m[4], l[4];
    f32x4 o[4] = {};
#pragma unroll
    for (int j = 0; j < 4; ++j) { m[j] = -1e30f; l[j] = 0.f; }

    for (int k0 = 0; k0 < 1024; k0 += 32) {
        f32x4 s[2] = {};
#pragma unroll
        for (int kb = 0; kb < 2; ++kb)
#pragma unroll
            for (int kk = 0; kk < 2; ++kk) {
                f16x8 kf = *(const f16x8*)(Kb + (size_t)(k0 + kb * 16 + lr) * 64 + kk * 32 + lg * 8);
                s[kb] = __builtin_amdgcn_mfma_f32_16x16x32_f16(qf[kk], kf, s[kb], 0, 0, 0);
            }
        // online softmax, all 64 lanes (rows = lg*4+j, cols = kb*16+lr)
#pragma unroll
        for (int j = 0; j < 4; ++j) {
            float mx = fmaxf(s[0][j], s[1][j]);
            mx = fmaxf(mx, __shfl_xor(mx, 1));
            mx = fmaxf(mx, __shfl_xor(mx, 2));
            mx = fmaxf(mx, __shfl_xor(mx, 4));
            mx = fmaxf(mx, __shfl_xor(mx, 8));
            float mnew = fmaxf(m[j], mx);
            float corr = exp2f(m[j] - mnew);
            float p0 = exp2f(s[0][j] - mnew);
            float p1 = exp2f(s[1][j] - mnew);
            s[0][j] = p0; s[1][j] = p1;
            float rs = p0 + p1;
            rs += __shfl_xor(rs, 1);
            rs += __shfl_xor(rs, 2);
            rs += __shfl_xor(rs, 4);
            rs += __shfl_xor(rs, 8);
            l[j] = l[j] * corr + rs;
            m[j] = mnew;
#pragma unroll
            for (int db = 0; db < 4; ++db) o[db][j] *= corr;
        }
        // P (C-layout) -> LDS -> A-frag layout
#pragma unroll
        for (int kb = 0; kb < 2; ++kb)
#pragma unroll
            for (int j = 0; j < 4; ++j)
                Pl[wid][lg * 4 + j][kb * 16 + lr] = (_Float16)s[kb][j];
        f16x8 pf = *(const f16x8*)&Pl[wid][lr][lg * 8];
#pragma unroll
        for (int db = 0; db < 4; ++db) {
            f16x8 vf = *(const f16x8*)(Vb + (size_t)(db * 16 + lr) * 1024 + k0 + lg * 8);
            o[db] = __builtin_amdgcn_mfma_f32_16x16x32_f16(pf, vf, o[db], 0, 0, 0);
        }
    }
#pragma unroll
    for (int j = 0; j < 4; ++j) l[j] = 1.f / l[j];
#pragma unroll
    for (int db = 0; db < 4; ++db)
#pragma unroll
        for (int j = 0; j < 4; ++j) {
            size_t row = (size_t)b * 1024 + q0 + lg * 4 + j;
            int col = h * 64 + db * 16 + lr;
            attO[row * 1024 + col] = (_Float16)(o[db][j] * l[j]);
        }
}

// ---------------------------------------------------------------------------
extern "C" void kernel_launch(void* const* d_in, const int* in_sizes, int n_in,
                              void* d_out, int out_size, void* d_ws, size_t ws_size,
                              hipStream_t stream)
{
    const float* x    = (const float*)d_in[0];   // [4096][1024]
    const float* Wqkv = (const float*)d_in[1];   // [1024][3072]
    const float* bqkv = (const float*)d_in[2];   // [3072]
    const float* Wout = (const float*)d_in[3];   // [1024][1024]
    const float* bout = (const float*)d_in[4];   // [1024]
    float* out = (float*)d_out;                  // [4096][1024]

    char* ws = (char*)d_ws;
    _Float16* xb    = (_Float16*)(ws);                       // 8 MB  [4096][1024]
    _Float16* Vt    = (_Float16*)(ws);                       // aliases xb (xb dead after qkv GEMM)
    _Float16* Wqkvt = (_Float16*)(ws + ((size_t)8  << 20));  // 6 MB  [3072][1024]
    _Float16* Woutt = (_Float16*)(ws + ((size_t)14 << 20));  // 2 MB  [1024][1024]
    _Float16* Qh    = (_Float16*)(ws + ((size_t)16 << 20));  // 8 MB  [64][1024][64]
    _Float16* Kh    = (_Float16*)(ws + ((size_t)24 << 20));  // 8 MB
    _Float16* Vh    = (_Float16*)(ws + ((size_t)32 << 20));  // 8 MB
    _Float16* attO  = (_Float16*)(ws + ((size_t)40 << 20));  // 8 MB  [4096][1024]
    // total 48 MB

    // 1. convert / transpose weights & activations to f16
    cvt_f32_f16<<<2048, 256, 0, stream>>>(x, xb, 4096 * 1024 / 8);
    transpose_f32_to_f16<<<dim3(48, 16), 256, 0, stream>>>(Wqkv, Wqkvt, 1024, 3072);
    transpose_f32_to_f16<<<dim3(16, 16), 256, 0, stream>>>(Wout, Woutt, 1024, 1024);

    // 2. qkv GEMM with K/Q/V head-scatter epilogue
    gemm_f16<1><<<dim3(24, 32), 256, 0, stream>>>(
        xb, Wqkvt, bqkv, nullptr, Kh, Qh, Vh, 4096, 3072, 1024);

    // 3. V -> V^T per head (writes Vt over the now-dead xb region)
    transpose_f16<<<dim3(1, 16, 64), 256, 0, stream>>>(Vh, Vt, 1024, 64);

    // 4. flash attention
    attn_kernel<<<dim3(16, 64), 256, 0, stream>>>(Qh, Kh, Vt, attO);

    // 5. output projection
    gemm_f16<0><<<dim3(8, 32), 256, 0, stream>>>(
        attO, Woutt, bout, out, nullptr, nullptr, nullptr, 4096, 1024, 1024);
}